// Round 2
// baseline (278.603 us; speedup 1.0000x reference)
//
#include <hip/hip_runtime.h>
#include <math.h>

#define VOXSZ 0.04f
#define NV 9
#define NC 24
#define NH 120
#define NW 160
#define NBINS 32768   // 15-bit morton key of (x>>2, y>>2, z>>2), each 0..16

// ---------------------------------------------------------------------------
// ws layout:
//   [0,24):    3 f64 global accumulators (sum_z, sum_z2, n_valid)
//   [24,32):   2 f32 scalars (zmean, zstd)
//   [64, +FT): feats transposed to (V,H,W,C)            (16.6 MB)
//   then:      hist[NBINS] int, ofs[NBINS] int, perm[N] int
// zsum per-voxel staged in out[n*25+24], overwritten by znorm pass.
// ---------------------------------------------------------------------------

__global__ void zero_acc_k(double* a) { a[0] = 0.0; a[1] = 0.0; a[2] = 0.0; }

__global__ void zero_hist_k(int* h) {
  int i = blockIdx.x * blockDim.x + threadIdx.x;
  if (i < NBINS) h[i] = 0;
}

__device__ __forceinline__ int morton5(int a) {  // spread 5 bits -> every 3rd bit
  a = (a | (a << 8)) & 0x100F;
  a = (a | (a << 4)) & 0x10C3;
  a = (a | (a << 2)) & 0x1249;
  return a;
}

__device__ __forceinline__ int voxel_key(int4 cd) {
  int xc = cd.y >> 2, yc = cd.z >> 2, zc = cd.w >> 2;
  xc = min(max(xc, 0), 16); yc = min(max(yc, 0), 16); zc = min(max(zc, 0), 16);
  return morton5(xc) | (morton5(yc) << 1) | (morton5(zc) << 2);
}

__global__ void hist_k(const int4* __restrict__ coords, int* __restrict__ hist, int N) {
  int n = blockIdx.x * blockDim.x + threadIdx.x;
  if (n >= N) return;
  atomicAdd(&hist[voxel_key(coords[n])], 1);
}

// single-block exclusive scan of hist -> ofs (NBINS elements)
__global__ __launch_bounds__(256) void scan_k(const int* __restrict__ hist,
                                              int* __restrict__ ofs) {
  __shared__ int ssum[256];
  int tid = threadIdx.x;
  const int per = NBINS / 256;  // 128
  int base = tid * per;
  int s = 0;
  for (int i = 0; i < per; ++i) s += hist[base + i];
  ssum[tid] = s;
  __syncthreads();
  for (int off = 1; off < 256; off <<= 1) {
    int v = (tid >= off) ? ssum[tid - off] : 0;
    __syncthreads();
    ssum[tid] += v;
    __syncthreads();
  }
  int pre = (tid == 0) ? 0 : ssum[tid - 1];
  for (int i = 0; i < per; ++i) {
    int h = hist[base + i];
    ofs[base + i] = pre;
    pre += h;
  }
}

__global__ void scatter_k(const int4* __restrict__ coords, int* __restrict__ ofs,
                          int* __restrict__ perm, int N) {
  int n = blockIdx.x * blockDim.x + threadIdx.x;
  if (n >= N) return;
  int pos = atomicAdd(&ofs[voxel_key(coords[n])], 1);
  perm[pos] = n;
}

__global__ void transpose_feats_k(const float* __restrict__ in, float* __restrict__ out) {
  int idx = blockIdx.x * blockDim.x + threadIdx.x;
  const int total = NV * NC * NH * NW;
  if (idx >= total) return;
  int w = idx % NW;
  int t = idx / NW;
  int h = t % NH; t /= NH;
  int c = t % NC;
  int v = t / NC;
  out[(((size_t)v * NH + h) * NW + w) * NC + c] = in[idx];
}

template <bool TR>
__global__ __launch_bounds__(256)
void bp_main_k(const int4* __restrict__ coords,
               const float* __restrict__ origin,
               const float* __restrict__ proj,
               const float* __restrict__ feats,
               const int* __restrict__ perm,   // may be null -> identity
               float* __restrict__ out,
               double* __restrict__ accums,
               int N)
{
  __shared__ float s_proj[NV * 12];
  __shared__ float s_org[3];
  int tid = threadIdx.x;
  if (tid < NV * 12) {
    int v = tid / 12, r = tid % 12;
    s_proj[tid] = proj[v * 16 + r];
  }
  if (tid < 3) s_org[tid] = origin[tid];
  __syncthreads();

  // XCD-aware bijective block swizzle: give each XCD a contiguous sorted chunk
  int nwg = gridDim.x;
  int orig = blockIdx.x;
  int xcd = orig & 7;
  int q = nwg >> 3, r = nwg & 7;
  int bid = (xcd < r ? xcd * (q + 1) : r * (q + 1) + (xcd - r) * q) + (orig >> 3);

  int i = bid * 256 + tid;
  int n = -1;
  if (i < N) n = perm ? perm[i] : i;

  float acc[NC];
#pragma unroll
  for (int c = 0; c < NC; ++c) acc[c] = 0.f;
  float zs = 0.f;
  int cnt = 0;

  if (n >= 0) {
    int4 cd = coords[n];
    float wx = (float)cd.y * VOXSZ + s_org[0];
    float wy = (float)cd.z * VOXSZ + s_org[1];
    float wz = (float)cd.w * VOXSZ + s_org[2];
#pragma unroll
    for (int v = 0; v < NV; ++v) {
      const float* P = &s_proj[v * 12];
      float ix = P[0] * wx + P[1] * wy + P[2]  * wz + P[3];
      float iy = P[4] * wx + P[5] * wy + P[6]  * wz + P[7];
      float iz = P[8] * wx + P[9] * wy + P[10] * wz + P[11];
      float px = ix / iz;
      float py = iy / iz;
      bool inb = (px >= 0.f) && (px <= (float)(NW - 1)) &&
                 (py >= 0.f) && (py <= (float)(NH - 1)) && (iz > 0.f);
      if (!inb) continue;
      cnt++; zs += iz;
      float x0f = floorf(px), y0f = floorf(py);
      float fx1 = px - x0f, fy1 = py - y0f;
      float fx0 = 1.f - fx1, fy0 = 1.f - fy1;
      int x0 = (int)x0f, y0 = (int)y0f;
      // x1==NW only possible when px==NW-1 exactly => weight 0, clamp is exact
      int x1 = (x0 + 1 < NW) ? x0 + 1 : NW - 1;
      int y1 = (y0 + 1 < NH) ? y0 + 1 : NH - 1;
      float w00 = fx0 * fy0, w10 = fx1 * fy0, w01 = fx0 * fy1, w11 = fx1 * fy1;
      if (TR) {
        const float4* p00 = (const float4*)(feats + (((size_t)v * NH + y0) * NW + x0) * NC);
        const float4* p10 = (const float4*)(feats + (((size_t)v * NH + y0) * NW + x1) * NC);
        const float4* p01 = (const float4*)(feats + (((size_t)v * NH + y1) * NW + x0) * NC);
        const float4* p11 = (const float4*)(feats + (((size_t)v * NH + y1) * NW + x1) * NC);
#pragma unroll
        for (int qq = 0; qq < NC / 4; ++qq) {
          float4 f00 = p00[qq], f10 = p10[qq], f01 = p01[qq], f11 = p11[qq];
          acc[qq * 4 + 0] += f00.x * w00 + f10.x * w10 + f01.x * w01 + f11.x * w11;
          acc[qq * 4 + 1] += f00.y * w00 + f10.y * w10 + f01.y * w01 + f11.y * w11;
          acc[qq * 4 + 2] += f00.z * w00 + f10.z * w10 + f01.z * w01 + f11.z * w11;
          acc[qq * 4 + 3] += f00.w * w00 + f10.w * w10 + f01.w * w01 + f11.w * w11;
        }
      } else {
        const float* base = feats + (size_t)v * NC * NH * NW;
#pragma unroll
        for (int c = 0; c < NC; ++c) {
          const float* pc = base + (size_t)c * NH * NW;
          float f00 = pc[y0 * NW + x0], f10 = pc[y0 * NW + x1];
          float f01 = pc[y1 * NW + x0], f11 = pc[y1 * NW + x1];
          acc[c] += f00 * w00 + f10 * w10 + f01 * w01 + f11 * w11;
        }
      }
    }
  }

  float zsv = 0.f;
  if (n >= 0) {
    float denom = (cnt > 0) ? (float)cnt : 1.f;
    size_t row = (size_t)n * (NC + 1);
#pragma unroll
    for (int c = 0; c < NC; ++c) out[row + c] = acc[c] / denom;
    zsv = zs / denom;
    out[row + NC] = zsv;                          // temp stage of zsum (col 24)
    out[(size_t)N * (NC + 1) + n] = (float)cnt;   // count output
  }

  // global reductions (f64): sum(zsum*valid), sum(zsum^2*valid), sum(valid)
  double rz = 0.0, rz2 = 0.0, rv = 0.0;
  if (n >= 0 && cnt > 0) {
    rz = (double)zsv;
    rz2 = (double)zsv * (double)zsv;
    rv = 1.0;
  }
#pragma unroll
  for (int off = 32; off > 0; off >>= 1) {
    rz  += __shfl_down(rz,  off, 64);
    rz2 += __shfl_down(rz2, off, 64);
    rv  += __shfl_down(rv,  off, 64);
  }
  if ((tid & 63) == 0) {
    atomicAdd(&accums[0], rz);
    atomicAdd(&accums[1], rz2);
    atomicAdd(&accums[2], rv);
  }
}

__global__ void finalize_k(const double* __restrict__ accums, float* __restrict__ scal) {
  double sz = accums[0], sz2 = accums[1], nv = accums[2];
  double nvm = (nv > 1.0) ? nv : 1.0;            // max(sum(valid), 1)
  double zmean = sz / nvm;
  double var = sz2 - 2.0 * zmean * sz + zmean * zmean * nv;
  if (var < 0.0) var = 0.0;
  double zstd = sqrt(var) + 1e-5;
  scal[0] = (float)zmean;
  scal[1] = (float)zstd;
}

__global__ void znorm_k(const float* __restrict__ scal, float* __restrict__ out, int N) {
  int n = blockIdx.x * blockDim.x + threadIdx.x;
  if (n >= N) return;
  float zmean = scal[0], zstd = scal[1];
  size_t row = (size_t)n * (NC + 1);
  float zsv = out[row + NC];
  float cntf = out[(size_t)N * (NC + 1) + n];
  out[row + NC] = (cntf > 0.f) ? (zsv - zmean) / zstd : 0.f;
}

extern "C" void kernel_launch(void* const* d_in, const int* in_sizes, int n_in,
                              void* d_out, int out_size, void* d_ws, size_t ws_size,
                              hipStream_t stream) {
  const int4*  coords = (const int4*)d_in[0];
  const float* origin = (const float*)d_in[1];
  const float* feats  = (const float*)d_in[2];
  const float* proj   = (const float*)d_in[3];
  float* out = (float*)d_out;
  int N = in_sizes[0] / 4;

  const size_t FT = (size_t)NV * NH * NW * NC;        // transposed feats elems
  char* ws = (char*)d_ws;
  double* accums = (double*)ws;                        // 3 doubles
  float*  scal   = (float*)(ws + 3 * sizeof(double));  // 2 floats
  size_t off = 64;
  float* featsT = (float*)(ws + off); off += FT * sizeof(float);
  bool use_tr = (ws_size >= off);
  int* hist = (int*)(ws + off); off += NBINS * sizeof(int);
  int* ofs  = (int*)(ws + off); off += NBINS * sizeof(int);
  int* perm = (int*)(ws + off); off += (size_t)N * sizeof(int);
  bool use_sort = use_tr && (ws_size >= off);

  zero_acc_k<<<1, 1, 0, stream>>>(accums);
  int blocks = (N + 255) / 256;

  const int* perm_arg = nullptr;
  if (use_sort) {
    zero_hist_k<<<NBINS / 256, 256, 0, stream>>>(hist);
    hist_k<<<blocks, 256, 0, stream>>>(coords, hist, N);
    scan_k<<<1, 256, 0, stream>>>(hist, ofs);
    scatter_k<<<blocks, 256, 0, stream>>>(coords, ofs, perm, N);
    perm_arg = perm;
  }

  if (use_tr) {
    transpose_feats_k<<<(int)((FT + 255) / 256), 256, 0, stream>>>(feats, featsT);
    bp_main_k<true><<<blocks, 256, 0, stream>>>(coords, origin, proj, featsT, perm_arg, out, accums, N);
  } else {
    bp_main_k<false><<<blocks, 256, 0, stream>>>(coords, origin, proj, feats, perm_arg, out, accums, N);
  }
  finalize_k<<<1, 1, 0, stream>>>(accums, scal);
  znorm_k<<<blocks, 256, 0, stream>>>(scal, out, N);
}

// Round 3
// 266.932 us; speedup vs baseline: 1.0437x; 1.0437x over previous
//
#include <hip/hip_runtime.h>
#include <hip/hip_fp16.h>
#include <math.h>

#define VOXSZ 0.04f
#define NV 9
#define NC 24
#define NH 120
#define NW 160
#define NBINS 32768   // 15-bit morton key of (x>>2, y>>2, z>>2), each 0..16

// ---------------------------------------------------------------------------
// ws layout:
//   [0,24):   3 f64 accumulators (sum_zsum, sum_zsum^2, n_valid)
//   [24,32):  2 f32 scalars (zmean, zstd)
//   [64, +11.06MB): featsT as fp16, 64 B per pixel:
//       half-slots [0..11]=ch0-11, [12..15]=pad, [16..27]=ch12-23, [28..31]=pad
//   then: hist[NBINS] int, ofs[NBINS] int, perm[N] int
// ---------------------------------------------------------------------------

__global__ void zero_k(int* hist, double* accums) {
  int i = blockIdx.x * blockDim.x + threadIdx.x;
  if (i < NBINS) hist[i] = 0;
  if (i < 3) accums[i] = 0.0;
}

__device__ __forceinline__ int morton5(int a) {
  a = (a | (a << 8)) & 0x100F;
  a = (a | (a << 4)) & 0x10C3;
  a = (a | (a << 2)) & 0x1249;
  return a;
}

__device__ __forceinline__ int voxel_key(int4 cd) {
  int xc = cd.y >> 2, yc = cd.z >> 2, zc = cd.w >> 2;
  xc = min(max(xc, 0), 16); yc = min(max(yc, 0), 16); zc = min(max(zc, 0), 16);
  return morton5(xc) | (morton5(yc) << 1) | (morton5(zc) << 2);
}

// Projection-only pass: histogram for the sort + global depth statistics.
__global__ __launch_bounds__(256)
void depth_hist_k(const int4* __restrict__ coords, const float* __restrict__ origin,
                  const float* __restrict__ proj, int* __restrict__ hist,
                  double* __restrict__ accums, int N) {
  __shared__ float s_proj[NV * 12];
  __shared__ float s_org[3];
  int tid = threadIdx.x;
  if (tid < NV * 12) s_proj[tid] = proj[(tid / 12) * 16 + (tid % 12)];
  if (tid < 3) s_org[tid] = origin[tid];
  __syncthreads();

  int n = blockIdx.x * blockDim.x + tid;
  double rz = 0.0, rz2 = 0.0, rv = 0.0;
  if (n < N) {
    int4 cd = coords[n];
    if (hist) atomicAdd(&hist[voxel_key(cd)], 1);
    float wx = (float)cd.y * VOXSZ + s_org[0];
    float wy = (float)cd.z * VOXSZ + s_org[1];
    float wz = (float)cd.w * VOXSZ + s_org[2];
    float zs = 0.f; int cnt = 0;
#pragma unroll
    for (int v = 0; v < NV; ++v) {
      const float* P = &s_proj[v * 12];
      float ix = P[0] * wx + P[1] * wy + P[2]  * wz + P[3];
      float iy = P[4] * wx + P[5] * wy + P[6]  * wz + P[7];
      float iz = P[8] * wx + P[9] * wy + P[10] * wz + P[11];
      float px = ix / iz, py = iy / iz;
      bool inb = (px >= 0.f) && (px <= (float)(NW - 1)) &&
                 (py >= 0.f) && (py <= (float)(NH - 1)) && (iz > 0.f);
      if (inb) { cnt++; zs += iz; }
    }
    if (cnt > 0) {
      float zsv = zs / (float)cnt;
      rz = (double)zsv; rz2 = (double)zsv * (double)zsv; rv = 1.0;
    }
  }
#pragma unroll
  for (int off = 32; off > 0; off >>= 1) {
    rz  += __shfl_down(rz,  off, 64);
    rz2 += __shfl_down(rz2, off, 64);
    rv  += __shfl_down(rv,  off, 64);
  }
  if ((tid & 63) == 0) {
    atomicAdd(&accums[0], rz);
    atomicAdd(&accums[1], rz2);
    atomicAdd(&accums[2], rv);
  }
}

// single-block scan, 1024 threads x 32 bins
__global__ __launch_bounds__(1024)
void scan_k(const int* __restrict__ hist, int* __restrict__ ofs) {
  __shared__ int ssum[1024];
  int tid = threadIdx.x;
  int base = tid * 32;
  int s = 0;
  for (int i = 0; i < 32; ++i) s += hist[base + i];
  ssum[tid] = s;
  __syncthreads();
  for (int off = 1; off < 1024; off <<= 1) {
    int v = (tid >= off) ? ssum[tid - off] : 0;
    __syncthreads();
    ssum[tid] += v;
    __syncthreads();
  }
  int pre = (tid == 0) ? 0 : ssum[tid - 1];
  for (int i = 0; i < 32; ++i) {
    int h = hist[base + i];
    ofs[base + i] = pre;
    pre += h;
  }
}

__global__ void scatter_k(const int4* __restrict__ coords, int* __restrict__ ofs,
                          int* __restrict__ perm, int N) {
  int n = blockIdx.x * blockDim.x + threadIdx.x;
  if (n >= N) return;
  int pos = atomicAdd(&ofs[voxel_key(coords[n])], 1);
  perm[pos] = n;
}

__global__ void finalize_k(const double* __restrict__ accums, float* __restrict__ scal) {
  double sz = accums[0], sz2 = accums[1], nv = accums[2];
  double nvm = (nv > 1.0) ? nv : 1.0;
  double zmean = sz / nvm;
  double var = sz2 - 2.0 * zmean * sz + zmean * zmean * nv;
  if (var < 0.0) var = 0.0;
  double zstd = sqrt(var) + 1e-5;
  scal[0] = (float)zmean;
  scal[1] = (float)zstd;
}

// f32 (V,C,H,W) -> fp16 (V,H,W, 64B-padded channel block), LDS-tiled full-line writes
__global__ __launch_bounds__(256)
void transpose_feats_k(const float* __restrict__ in, __half* __restrict__ outT) {
  int vh = blockIdx.x;            // v*NH + h
  int v = vh / NH, h = vh % NH;
  __shared__ __half s[NC][NW + 2];
  const float* ibase = in + (size_t)v * NC * NH * NW + (size_t)h * NW;
  for (int e = threadIdx.x; e < NC * NW; e += 256) {
    int c = e / NW, w = e - c * NW;
    s[c][w] = __float2half(ibase[(size_t)c * NH * NW + w]);
  }
  __syncthreads();
  unsigned int* obase = (unsigned int*)outT + (size_t)vh * NW * 16;
  for (int j = threadIdx.x; j < NW * 16; j += 256) {
    int w = j >> 4, k = j & 15;
    unsigned int val = 0;
    if (k < 6) {
      __half2 hv = __halves2half2(s[2 * k][w], s[2 * k + 1][w]);
      val = *(unsigned int*)&hv;
    } else if (k >= 8 && k < 14) {
      __half2 hv = __halves2half2(s[2 * k - 4][w], s[2 * k - 3][w]);
      val = *(unsigned int*)&hv;
    }
    obase[j] = val;
  }
}

__device__ __forceinline__ void unpack_acc(float4 a, float2 b, float w, float* acc) {
  const __half2* ha = (const __half2*)&a;
  const __half2* hb = (const __half2*)&b;
#pragma unroll
  for (int i = 0; i < 4; ++i) {
    float2 t = __half22float2(ha[i]);
    acc[2 * i] += w * t.x; acc[2 * i + 1] += w * t.y;
  }
#pragma unroll
  for (int i = 0; i < 2; ++i) {
    float2 t = __half22float2(hb[i]);
    acc[8 + 2 * i] += w * t.x; acc[9 + 2 * i] += w * t.y;
  }
}

// Main gather: 2 threads per voxel (12 channels each), fp16 featsT.
__global__ __launch_bounds__(256, 8)
void bp_gather_k(const int4* __restrict__ coords, const float* __restrict__ origin,
                 const float* __restrict__ proj, const __half* __restrict__ featsT,
                 const int* __restrict__ perm, const float* __restrict__ scal,
                 float* __restrict__ out, int N) {
  __shared__ float s_proj[NV * 12];
  __shared__ float s_org[3];
  __shared__ float s_scal[2];
  int tid = threadIdx.x;
  if (tid < NV * 12) s_proj[tid] = proj[(tid / 12) * 16 + (tid % 12)];
  if (tid < 3) s_org[tid] = origin[tid];
  if (tid < 2) s_scal[tid] = scal[tid];
  __syncthreads();

  int nwg = gridDim.x, orig = blockIdx.x;
  int xcd = orig & 7, q = nwg >> 3, r = nwg & 7;
  int bid = (xcd < r ? xcd * (q + 1) : r * (q + 1) + (xcd - r) * q) + (orig >> 3);

  int idx = bid * 256 + tid;
  int vox = idx >> 1, hh = idx & 1;
  if (vox >= N) return;
  int n = perm ? perm[vox] : vox;

  int4 cd = coords[n];
  float wx = (float)cd.y * VOXSZ + s_org[0];
  float wy = (float)cd.z * VOXSZ + s_org[1];
  float wz = (float)cd.w * VOXSZ + s_org[2];

  float acc[12];
#pragma unroll
  for (int c = 0; c < 12; ++c) acc[c] = 0.f;
  float zs = 0.f; int cnt = 0;
  const char* fbase = (const char*)featsT + hh * 32;

#pragma unroll
  for (int v = 0; v < NV; ++v) {
    const float* P = &s_proj[v * 12];
    float ix = P[0] * wx + P[1] * wy + P[2]  * wz + P[3];
    float iy = P[4] * wx + P[5] * wy + P[6]  * wz + P[7];
    float iz = P[8] * wx + P[9] * wy + P[10] * wz + P[11];
    float px = ix / iz, py = iy / iz;
    bool inb = (px >= 0.f) && (px <= (float)(NW - 1)) &&
               (py >= 0.f) && (py <= (float)(NH - 1)) && (iz > 0.f);
    if (!inb) continue;
    cnt++; zs += iz;
    float x0f = floorf(px), y0f = floorf(py);
    float fx1 = px - x0f, fy1 = py - y0f;
    float fx0 = 1.f - fx1, fy0 = 1.f - fy1;
    int x0 = (int)x0f, y0 = (int)y0f;
    // x1==NW (y1==NH) only when weight is exactly 0 -> clamp is exact
    int dx = (x0 + 1 < NW) ? 64 : 0;
    int dy = (y0 + 1 < NH) ? NW * 64 : 0;
    const char* p00 = fbase + (size_t)((y0 + v * NH) * NW + x0) * 64;
    float w00 = fx0 * fy0, w10 = fx1 * fy0, w01 = fx0 * fy1, w11 = fx1 * fy1;
    float4 a00 = *(const float4*)p00;
    float2 b00 = *(const float2*)(p00 + 16);
    float4 a10 = *(const float4*)(p00 + dx);
    float2 b10 = *(const float2*)(p00 + dx + 16);
    float4 a01 = *(const float4*)(p00 + dy);
    float2 b01 = *(const float2*)(p00 + dy + 16);
    float4 a11 = *(const float4*)(p00 + dx + dy);
    float2 b11 = *(const float2*)(p00 + dx + dy + 16);
    unpack_acc(a00, b00, w00, acc);
    unpack_acc(a10, b10, w10, acc);
    unpack_acc(a01, b01, w01, acc);
    unpack_acc(a11, b11, w11, acc);
  }

  float denom = (cnt > 0) ? (float)cnt : 1.f;
  float inv = 1.f / denom;
  size_t row = (size_t)n * (NC + 1) + hh * 12;
#pragma unroll
  for (int c = 0; c < 12; ++c) out[row + c] = acc[c] * inv;
  if (hh) {
    float zsv = zs * inv;
    out[(size_t)n * (NC + 1) + NC] = (cnt > 0) ? (zsv - s_scal[0]) / s_scal[1] : 0.f;
    out[(size_t)N * (NC + 1) + n] = (float)cnt;
  }
}

// Fallback (ws too small): 1 thread/voxel, f32 strided gather from original feats.
__global__ __launch_bounds__(256)
void bp_fallback_k(const int4* __restrict__ coords, const float* __restrict__ origin,
                   const float* __restrict__ proj, const float* __restrict__ feats,
                   const float* __restrict__ scal, float* __restrict__ out, int N) {
  __shared__ float s_proj[NV * 12];
  __shared__ float s_org[3];
  __shared__ float s_scal[2];
  int tid = threadIdx.x;
  if (tid < NV * 12) s_proj[tid] = proj[(tid / 12) * 16 + (tid % 12)];
  if (tid < 3) s_org[tid] = origin[tid];
  if (tid < 2) s_scal[tid] = scal[tid];
  __syncthreads();
  int n = blockIdx.x * blockDim.x + tid;
  if (n >= N) return;
  int4 cd = coords[n];
  float wx = (float)cd.y * VOXSZ + s_org[0];
  float wy = (float)cd.z * VOXSZ + s_org[1];
  float wz = (float)cd.w * VOXSZ + s_org[2];
  float acc[NC];
#pragma unroll
  for (int c = 0; c < NC; ++c) acc[c] = 0.f;
  float zs = 0.f; int cnt = 0;
#pragma unroll
  for (int v = 0; v < NV; ++v) {
    const float* P = &s_proj[v * 12];
    float ix = P[0] * wx + P[1] * wy + P[2]  * wz + P[3];
    float iy = P[4] * wx + P[5] * wy + P[6]  * wz + P[7];
    float iz = P[8] * wx + P[9] * wy + P[10] * wz + P[11];
    float px = ix / iz, py = iy / iz;
    bool inb = (px >= 0.f) && (px <= (float)(NW - 1)) &&
               (py >= 0.f) && (py <= (float)(NH - 1)) && (iz > 0.f);
    if (!inb) continue;
    cnt++; zs += iz;
    float x0f = floorf(px), y0f = floorf(py);
    float fx1 = px - x0f, fy1 = py - y0f;
    float fx0 = 1.f - fx1, fy0 = 1.f - fy1;
    int x0 = (int)x0f, y0 = (int)y0f;
    int x1 = (x0 + 1 < NW) ? x0 + 1 : NW - 1;
    int y1 = (y0 + 1 < NH) ? y0 + 1 : NH - 1;
    float w00 = fx0 * fy0, w10 = fx1 * fy0, w01 = fx0 * fy1, w11 = fx1 * fy1;
    const float* base = feats + (size_t)v * NC * NH * NW;
#pragma unroll
    for (int c = 0; c < NC; ++c) {
      const float* pc = base + (size_t)c * NH * NW;
      acc[c] += pc[y0 * NW + x0] * w00 + pc[y0 * NW + x1] * w10 +
                pc[y1 * NW + x0] * w01 + pc[y1 * NW + x1] * w11;
    }
  }
  float denom = (cnt > 0) ? (float)cnt : 1.f;
  float inv = 1.f / denom;
  size_t row = (size_t)n * (NC + 1);
#pragma unroll
  for (int c = 0; c < NC; ++c) out[row + c] = acc[c] * inv;
  float zsv = zs * inv;
  out[row + NC] = (cnt > 0) ? (zsv - s_scal[0]) / s_scal[1] : 0.f;
  out[(size_t)N * (NC + 1) + n] = (float)cnt;
}

extern "C" void kernel_launch(void* const* d_in, const int* in_sizes, int n_in,
                              void* d_out, int out_size, void* d_ws, size_t ws_size,
                              hipStream_t stream) {
  const int4*  coords = (const int4*)d_in[0];
  const float* origin = (const float*)d_in[1];
  const float* feats  = (const float*)d_in[2];
  const float* proj   = (const float*)d_in[3];
  float* out = (float*)d_out;
  int N = in_sizes[0] / 4;

  char* ws = (char*)d_ws;
  double* accums = (double*)ws;                        // 3 doubles
  float*  scal   = (float*)(ws + 3 * sizeof(double));  // 2 floats
  size_t off = 64;
  __half* featsT = (__half*)(ws + off);
  off += (size_t)NV * NH * NW * 64;                    // 64 B per pixel
  int* hist = (int*)(ws + off); off += NBINS * sizeof(int);
  int* ofs  = (int*)(ws + off); off += NBINS * sizeof(int);
  int* perm = (int*)(ws + off); off += (size_t)N * sizeof(int);
  bool full = (ws_size >= off);

  int blocksN = (N + 255) / 256;

  if (full) {
    zero_k<<<(NBINS + 255) / 256, 256, 0, stream>>>(hist, accums);
    depth_hist_k<<<blocksN, 256, 0, stream>>>(coords, origin, proj, hist, accums, N);
    transpose_feats_k<<<NV * NH, 256, 0, stream>>>(feats, featsT);
    scan_k<<<1, 1024, 0, stream>>>(hist, ofs);
    scatter_k<<<blocksN, 256, 0, stream>>>(coords, ofs, perm, N);
    finalize_k<<<1, 1, 0, stream>>>(accums, scal);
    bp_gather_k<<<2 * blocksN, 256, 0, stream>>>(coords, origin, proj, featsT, perm, scal, out, N);
  } else {
    zero_k<<<(NBINS + 255) / 256, 256, 0, stream>>>(nullptr, accums);
    depth_hist_k<<<blocksN, 256, 0, stream>>>(coords, origin, proj, nullptr, accums, N);
    finalize_k<<<1, 1, 0, stream>>>(accums, scal);
    bp_fallback_k<<<blocksN, 256, 0, stream>>>(coords, origin, proj, feats, scal, out, N);
  }
}

// Round 4
// 128.608 us; speedup vs baseline: 2.1663x; 2.0755x over previous
//
#include <hip/hip_runtime.h>
#include <hip/hip_fp16.h>
#include <math.h>

#define VOXSZ 0.04f
#define NV 9
#define NC 24
#define NH 120
#define NW 160
#define NBINS 32768   // 15-bit morton key of (x>>2, y>>2, z>>2), each 0..16

// ---------------------------------------------------------------------------
// ws layout:
//   [0,64):   2 f32 scalars (zmean, zstd)
//   [64, +32KB): per-block partials, 4 doubles each (z, z2, nvalid, pad)
//   then: featsT fp16 (64 B per pixel), hist[NBINS], ofs[NBINS], perm[N]
// featsT half-slots: [0..11]=ch0-11, [12..15]=pad, [16..27]=ch12-23, [28..31]=pad
// ---------------------------------------------------------------------------

#define MAXBLK 4096   // max partial slots

__global__ void zero_k(int* hist) {
  int i = blockIdx.x * blockDim.x + threadIdx.x;
  if (i < NBINS) hist[i] = 0;
}

__device__ __forceinline__ int morton5(int a) {
  a = (a | (a << 8)) & 0x100F;
  a = (a | (a << 4)) & 0x10C3;
  a = (a | (a << 2)) & 0x1249;
  return a;
}

__device__ __forceinline__ int voxel_key(int4 cd) {
  int xc = cd.y >> 2, yc = cd.z >> 2, zc = cd.w >> 2;
  xc = min(max(xc, 0), 16); yc = min(max(yc, 0), 16); zc = min(max(zc, 0), 16);
  return morton5(xc) | (morton5(yc) << 1) | (morton5(zc) << 2);
}

// Projection-only pass: histogram for the sort + per-block depth-stat partials.
__global__ __launch_bounds__(256)
void depth_hist_k(const int4* __restrict__ coords, const float* __restrict__ origin,
                  const float* __restrict__ proj, int* __restrict__ hist,
                  double* __restrict__ partials, int N) {
  __shared__ float s_proj[NV * 12];
  __shared__ float s_org[3];
  __shared__ double s_red[3][4];
  int tid = threadIdx.x;
  if (tid < NV * 12) s_proj[tid] = proj[(tid / 12) * 16 + (tid % 12)];
  if (tid < 3) s_org[tid] = origin[tid];
  __syncthreads();

  int n = blockIdx.x * blockDim.x + tid;
  double rz = 0.0, rz2 = 0.0, rv = 0.0;
  if (n < N) {
    int4 cd = coords[n];
    if (hist) atomicAdd(&hist[voxel_key(cd)], 1);
    float wx = (float)cd.y * VOXSZ + s_org[0];
    float wy = (float)cd.z * VOXSZ + s_org[1];
    float wz = (float)cd.w * VOXSZ + s_org[2];
    float zs = 0.f; int cnt = 0;
#pragma unroll
    for (int v = 0; v < NV; ++v) {
      const float* P = &s_proj[v * 12];
      float ix = P[0] * wx + P[1] * wy + P[2]  * wz + P[3];
      float iy = P[4] * wx + P[5] * wy + P[6]  * wz + P[7];
      float iz = P[8] * wx + P[9] * wy + P[10] * wz + P[11];
      float px = ix / iz, py = iy / iz;
      bool inb = (px >= 0.f) && (px <= (float)(NW - 1)) &&
                 (py >= 0.f) && (py <= (float)(NH - 1)) && (iz > 0.f);
      if (inb) { cnt++; zs += iz; }
    }
    if (cnt > 0) {
      float zsv = zs / (float)cnt;
      rz = (double)zsv; rz2 = (double)zsv * (double)zsv; rv = 1.0;
    }
  }
#pragma unroll
  for (int off = 32; off > 0; off >>= 1) {
    rz  += __shfl_down(rz,  off, 64);
    rz2 += __shfl_down(rz2, off, 64);
    rv  += __shfl_down(rv,  off, 64);
  }
  if ((tid & 63) == 0) {
    int w = tid >> 6;
    s_red[0][w] = rz; s_red[1][w] = rz2; s_red[2][w] = rv;
  }
  __syncthreads();
  if (tid == 0) {
    double a = 0, b = 0, c = 0;
#pragma unroll
    for (int w = 0; w < 4; ++w) { a += s_red[0][w]; b += s_red[1][w]; c += s_red[2][w]; }
    double* p = partials + (size_t)blockIdx.x * 4;
    p[0] = a; p[1] = b; p[2] = c;
  }
}

// single block: sum partials, compute zmean/zstd
__global__ __launch_bounds__(1024)
void reduce_finalize_k(const double* __restrict__ partials, int nblocks,
                       float* __restrict__ scal) {
  int tid = threadIdx.x;
  double rz = 0.0, rz2 = 0.0, rv = 0.0;
  for (int i = tid; i < nblocks; i += 1024) {
    const double* p = partials + (size_t)i * 4;
    rz += p[0]; rz2 += p[1]; rv += p[2];
  }
#pragma unroll
  for (int off = 32; off > 0; off >>= 1) {
    rz  += __shfl_down(rz,  off, 64);
    rz2 += __shfl_down(rz2, off, 64);
    rv  += __shfl_down(rv,  off, 64);
  }
  __shared__ double s[3][16];
  if ((tid & 63) == 0) {
    int w = tid >> 6;
    s[0][w] = rz; s[1][w] = rz2; s[2][w] = rv;
  }
  __syncthreads();
  if (tid == 0) {
    double sz = 0, sz2 = 0, nv = 0;
#pragma unroll
    for (int w = 0; w < 16; ++w) { sz += s[0][w]; sz2 += s[1][w]; nv += s[2][w]; }
    double nvm = (nv > 1.0) ? nv : 1.0;
    double zmean = sz / nvm;
    double var = sz2 - 2.0 * zmean * sz + zmean * zmean * nv;
    if (var < 0.0) var = 0.0;
    double zstd = sqrt(var) + 1e-5;
    scal[0] = (float)zmean;
    scal[1] = (float)zstd;
  }
}

// single-block scan, 1024 threads x 32 bins
__global__ __launch_bounds__(1024)
void scan_k(const int* __restrict__ hist, int* __restrict__ ofs) {
  __shared__ int ssum[1024];
  int tid = threadIdx.x;
  int base = tid * 32;
  int s = 0;
  for (int i = 0; i < 32; ++i) s += hist[base + i];
  ssum[tid] = s;
  __syncthreads();
  for (int off = 1; off < 1024; off <<= 1) {
    int v = (tid >= off) ? ssum[tid - off] : 0;
    __syncthreads();
    ssum[tid] += v;
    __syncthreads();
  }
  int pre = (tid == 0) ? 0 : ssum[tid - 1];
  for (int i = 0; i < 32; ++i) {
    int h = hist[base + i];
    ofs[base + i] = pre;
    pre += h;
  }
}

__global__ void scatter_k(const int4* __restrict__ coords, int* __restrict__ ofs,
                          int* __restrict__ perm, int N) {
  int n = blockIdx.x * blockDim.x + threadIdx.x;
  if (n >= N) return;
  int pos = atomicAdd(&ofs[voxel_key(coords[n])], 1);
  perm[pos] = n;
}

// f32 (V,C,H,W) -> fp16 (V,H,W, 64B-padded channel block), LDS-tiled
__global__ __launch_bounds__(256)
void transpose_feats_k(const float* __restrict__ in, __half* __restrict__ outT) {
  int vh = blockIdx.x;            // v*NH + h
  int v = vh / NH, h = vh % NH;
  __shared__ __half s[NC][NW + 2];
  const float* ibase = in + (size_t)v * NC * NH * NW + (size_t)h * NW;
  for (int e = threadIdx.x; e < NC * NW; e += 256) {
    int c = e / NW, w = e - c * NW;
    s[c][w] = __float2half(ibase[(size_t)c * NH * NW + w]);
  }
  __syncthreads();
  unsigned int* obase = (unsigned int*)outT + (size_t)vh * NW * 16;
  for (int j = threadIdx.x; j < NW * 16; j += 256) {
    int w = j >> 4, k = j & 15;
    unsigned int val = 0;
    if (k < 6) {
      __half2 hv = __halves2half2(s[2 * k][w], s[2 * k + 1][w]);
      val = *(unsigned int*)&hv;
    } else if (k >= 8 && k < 14) {
      __half2 hv = __halves2half2(s[2 * k - 4][w], s[2 * k - 3][w]);
      val = *(unsigned int*)&hv;
    }
    obase[j] = val;
  }
}

__device__ __forceinline__ void unpack_acc(float4 a, float2 b, float w, float* acc) {
  const __half2* ha = (const __half2*)&a;
  const __half2* hb = (const __half2*)&b;
#pragma unroll
  for (int i = 0; i < 4; ++i) {
    float2 t = __half22float2(ha[i]);
    acc[2 * i] += w * t.x; acc[2 * i + 1] += w * t.y;
  }
#pragma unroll
  for (int i = 0; i < 2; ++i) {
    float2 t = __half22float2(hb[i]);
    acc[8 + 2 * i] += w * t.x; acc[9 + 2 * i] += w * t.y;
  }
}

// Main gather: 2 threads per voxel (12 channels each), fp16 featsT.
__global__ __launch_bounds__(256, 8)
void bp_gather_k(const int4* __restrict__ coords, const float* __restrict__ origin,
                 const float* __restrict__ proj, const __half* __restrict__ featsT,
                 const int* __restrict__ perm, const float* __restrict__ scal,
                 float* __restrict__ out, int N) {
  __shared__ float s_proj[NV * 12];
  __shared__ float s_org[3];
  __shared__ float s_scal[2];
  int tid = threadIdx.x;
  if (tid < NV * 12) s_proj[tid] = proj[(tid / 12) * 16 + (tid % 12)];
  if (tid < 3) s_org[tid] = origin[tid];
  if (tid < 2) s_scal[tid] = scal[tid];
  __syncthreads();

  int nwg = gridDim.x, orig = blockIdx.x;
  int xcd = orig & 7, q = nwg >> 3, r = nwg & 7;
  int bid = (xcd < r ? xcd * (q + 1) : r * (q + 1) + (xcd - r) * q) + (orig >> 3);

  int idx = bid * 256 + tid;
  int vox = idx >> 1, hh = idx & 1;
  if (vox >= N) return;
  int n = perm ? perm[vox] : vox;

  int4 cd = coords[n];
  float wx = (float)cd.y * VOXSZ + s_org[0];
  float wy = (float)cd.z * VOXSZ + s_org[1];
  float wz = (float)cd.w * VOXSZ + s_org[2];

  float acc[12];
#pragma unroll
  for (int c = 0; c < 12; ++c) acc[c] = 0.f;
  float zs = 0.f; int cnt = 0;
  const char* fbase = (const char*)featsT + hh * 32;

#pragma unroll
  for (int v = 0; v < NV; ++v) {
    const float* P = &s_proj[v * 12];
    float ix = P[0] * wx + P[1] * wy + P[2]  * wz + P[3];
    float iy = P[4] * wx + P[5] * wy + P[6]  * wz + P[7];
    float iz = P[8] * wx + P[9] * wy + P[10] * wz + P[11];
    float px = ix / iz, py = iy / iz;
    bool inb = (px >= 0.f) && (px <= (float)(NW - 1)) &&
               (py >= 0.f) && (py <= (float)(NH - 1)) && (iz > 0.f);
    if (!inb) continue;
    cnt++; zs += iz;
    float x0f = floorf(px), y0f = floorf(py);
    float fx1 = px - x0f, fy1 = py - y0f;
    float fx0 = 1.f - fx1, fy0 = 1.f - fy1;
    int x0 = (int)x0f, y0 = (int)y0f;
    // x1==NW (y1==NH) only when weight is exactly 0 -> clamp is exact
    int dx = (x0 + 1 < NW) ? 64 : 0;
    int dy = (y0 + 1 < NH) ? NW * 64 : 0;
    const char* p00 = fbase + (size_t)((y0 + v * NH) * NW + x0) * 64;
    float w00 = fx0 * fy0, w10 = fx1 * fy0, w01 = fx0 * fy1, w11 = fx1 * fy1;
    float4 a00 = *(const float4*)p00;
    float2 b00 = *(const float2*)(p00 + 16);
    float4 a10 = *(const float4*)(p00 + dx);
    float2 b10 = *(const float2*)(p00 + dx + 16);
    float4 a01 = *(const float4*)(p00 + dy);
    float2 b01 = *(const float2*)(p00 + dy + 16);
    float4 a11 = *(const float4*)(p00 + dx + dy);
    float2 b11 = *(const float2*)(p00 + dx + dy + 16);
    unpack_acc(a00, b00, w00, acc);
    unpack_acc(a10, b10, w10, acc);
    unpack_acc(a01, b01, w01, acc);
    unpack_acc(a11, b11, w11, acc);
  }

  float denom = (cnt > 0) ? (float)cnt : 1.f;
  float inv = 1.f / denom;
  size_t row = (size_t)n * (NC + 1) + hh * 12;
#pragma unroll
  for (int c = 0; c < 12; ++c) out[row + c] = acc[c] * inv;
  if (hh) {
    float zsv = zs * inv;
    out[(size_t)n * (NC + 1) + NC] = (cnt > 0) ? (zsv - s_scal[0]) / s_scal[1] : 0.f;
    out[(size_t)N * (NC + 1) + n] = (float)cnt;
  }
}

// Fallback (ws too small for featsT+sort): 1 thread/voxel, f32 strided gather.
__global__ __launch_bounds__(256)
void bp_fallback_k(const int4* __restrict__ coords, const float* __restrict__ origin,
                   const float* __restrict__ proj, const float* __restrict__ feats,
                   const float* __restrict__ scal, float* __restrict__ out, int N) {
  __shared__ float s_proj[NV * 12];
  __shared__ float s_org[3];
  __shared__ float s_scal[2];
  int tid = threadIdx.x;
  if (tid < NV * 12) s_proj[tid] = proj[(tid / 12) * 16 + (tid % 12)];
  if (tid < 3) s_org[tid] = origin[tid];
  if (tid < 2) s_scal[tid] = scal[tid];
  __syncthreads();
  int n = blockIdx.x * blockDim.x + tid;
  if (n >= N) return;
  int4 cd = coords[n];
  float wx = (float)cd.y * VOXSZ + s_org[0];
  float wy = (float)cd.z * VOXSZ + s_org[1];
  float wz = (float)cd.w * VOXSZ + s_org[2];
  float acc[NC];
#pragma unroll
  for (int c = 0; c < NC; ++c) acc[c] = 0.f;
  float zs = 0.f; int cnt = 0;
#pragma unroll
  for (int v = 0; v < NV; ++v) {
    const float* P = &s_proj[v * 12];
    float ix = P[0] * wx + P[1] * wy + P[2]  * wz + P[3];
    float iy = P[4] * wx + P[5] * wy + P[6]  * wz + P[7];
    float iz = P[8] * wx + P[9] * wy + P[10] * wz + P[11];
    float px = ix / iz, py = iy / iz;
    bool inb = (px >= 0.f) && (px <= (float)(NW - 1)) &&
               (py >= 0.f) && (py <= (float)(NH - 1)) && (iz > 0.f);
    if (!inb) continue;
    cnt++; zs += iz;
    float x0f = floorf(px), y0f = floorf(py);
    float fx1 = px - x0f, fy1 = py - y0f;
    float fx0 = 1.f - fx1, fy0 = 1.f - fy1;
    int x0 = (int)x0f, y0 = (int)y0f;
    int x1 = (x0 + 1 < NW) ? x0 + 1 : NW - 1;
    int y1 = (y0 + 1 < NH) ? y0 + 1 : NH - 1;
    float w00 = fx0 * fy0, w10 = fx1 * fy0, w01 = fx0 * fy1, w11 = fx1 * fy1;
    const float* base = feats + (size_t)v * NC * NH * NW;
#pragma unroll
    for (int c = 0; c < NC; ++c) {
      const float* pc = base + (size_t)c * NH * NW;
      acc[c] += pc[y0 * NW + x0] * w00 + pc[y0 * NW + x1] * w10 +
                pc[y1 * NW + x0] * w01 + pc[y1 * NW + x1] * w11;
    }
  }
  float denom = (cnt > 0) ? (float)cnt : 1.f;
  float inv = 1.f / denom;
  size_t row = (size_t)n * (NC + 1);
#pragma unroll
  for (int c = 0; c < NC; ++c) out[row + c] = acc[c] * inv;
  float zsv = zs * inv;
  out[row + NC] = (cnt > 0) ? (zsv - s_scal[0]) / s_scal[1] : 0.f;
  out[(size_t)N * (NC + 1) + n] = (float)cnt;
}

extern "C" void kernel_launch(void* const* d_in, const int* in_sizes, int n_in,
                              void* d_out, int out_size, void* d_ws, size_t ws_size,
                              hipStream_t stream) {
  const int4*  coords = (const int4*)d_in[0];
  const float* origin = (const float*)d_in[1];
  const float* feats  = (const float*)d_in[2];
  const float* proj   = (const float*)d_in[3];
  float* out = (float*)d_out;
  int N = in_sizes[0] / 4;

  char* ws = (char*)d_ws;
  float*  scal     = (float*)ws;                 // 2 floats
  double* partials = (double*)(ws + 64);         // MAXBLK*4 doubles (128 KB max)
  size_t off = 64 + (size_t)MAXBLK * 4 * sizeof(double);
  __half* featsT = (__half*)(ws + off);
  off += (size_t)NV * NH * NW * 64;              // 64 B per pixel
  int* hist = (int*)(ws + off); off += NBINS * sizeof(int);
  int* ofs  = (int*)(ws + off); off += NBINS * sizeof(int);
  int* perm = (int*)(ws + off); off += (size_t)N * sizeof(int);
  bool full = (ws_size >= off);

  int blocksN = (N + 255) / 256;
  if (blocksN > MAXBLK) blocksN = MAXBLK;   // N fixed at 262144 -> 1024; safety
  int blocksAll = (N + 255) / 256;

  if (full) {
    zero_k<<<(NBINS + 255) / 256, 256, 0, stream>>>(hist);
    depth_hist_k<<<blocksN, 256, 0, stream>>>(coords, origin, proj, hist, partials, N);
    transpose_feats_k<<<NV * NH, 256, 0, stream>>>(feats, featsT);
    scan_k<<<1, 1024, 0, stream>>>(hist, ofs);
    scatter_k<<<blocksAll, 256, 0, stream>>>(coords, ofs, perm, N);
    reduce_finalize_k<<<1, 1024, 0, stream>>>(partials, blocksN, scal);
    bp_gather_k<<<2 * blocksAll, 256, 0, stream>>>(coords, origin, proj, featsT, perm, scal, out, N);
  } else {
    depth_hist_k<<<blocksN, 256, 0, stream>>>(coords, origin, proj, nullptr, partials, N);
    reduce_finalize_k<<<1, 1024, 0, stream>>>(partials, blocksN, scal);
    bp_fallback_k<<<blocksAll, 256, 0, stream>>>(coords, origin, proj, feats, scal, out, N);
  }
}

// Round 5
// 124.247 us; speedup vs baseline: 2.2423x; 1.0351x over previous
//
#include <hip/hip_runtime.h>
#include <hip/hip_fp16.h>
#include <math.h>

#define VOXSZ 0.04f
#define NV 9
#define NC 24
#define NH 120
#define NW 160
#define NBINS 32768   // 15-bit morton key of (x>>2, y>>2, z>>2), each 0..16

// ---------------------------------------------------------------------------
// ws layout:
//   [0,64):    2 f32 scalars (zmean, zstd)
//   [64,+):    per-block partials (4 doubles each)
//   then:      featsT fp16 48 B/pixel (ch0..23 dense), hist[NBINS], ofs[NBINS],
//              sorted[N] int4 records (x, y, z, orig_index)
// ---------------------------------------------------------------------------

__device__ __forceinline__ int morton5(int a) {
  a = (a | (a << 8)) & 0x100F;
  a = (a | (a << 4)) & 0x10C3;
  a = (a | (a << 2)) & 0x1249;
  return a;
}

__device__ __forceinline__ int voxel_key(int4 cd) {
  int xc = cd.y >> 2, yc = cd.z >> 2, zc = cd.w >> 2;
  xc = min(max(xc, 0), 16); yc = min(max(yc, 0), 16); zc = min(max(zc, 0), 16);
  return morton5(xc) | (morton5(yc) << 1) | (morton5(zc) << 2);
}

__global__ __launch_bounds__(256)
void hist_k(const int4* __restrict__ coords, int* __restrict__ hist, int N) {
  int n = blockIdx.x * blockDim.x + threadIdx.x;
  if (n < N) atomicAdd(&hist[voxel_key(coords[n])], 1);
}

// single-block scan, 1024 threads x 32 bins
__global__ __launch_bounds__(1024)
void scan_k(const int* __restrict__ hist, int* __restrict__ ofs) {
  __shared__ int ssum[1024];
  int tid = threadIdx.x;
  int base = tid * 32;
  int s = 0;
  for (int i = 0; i < 32; ++i) s += hist[base + i];
  ssum[tid] = s;
  __syncthreads();
  for (int off = 1; off < 1024; off <<= 1) {
    int v = (tid >= off) ? ssum[tid - off] : 0;
    __syncthreads();
    ssum[tid] += v;
    __syncthreads();
  }
  int pre = (tid == 0) ? 0 : ssum[tid - 1];
  for (int i = 0; i < 32; ++i) {
    int h = hist[base + i];
    ofs[base + i] = pre;
    pre += h;
  }
}

// scatter to sorted records + per-block depth-stat partials
__global__ __launch_bounds__(256)
void scatter_stats_k(const int4* __restrict__ coords, const float* __restrict__ origin,
                     const float* __restrict__ proj, int* __restrict__ ofs,
                     int4* __restrict__ sorted, double* __restrict__ partials, int N) {
  __shared__ float s_proj[NV * 12];
  __shared__ float s_org[3];
  __shared__ double s_red[3][4];
  int tid = threadIdx.x;
  if (tid < NV * 12) s_proj[tid] = proj[(tid / 12) * 16 + (tid % 12)];
  if (tid < 3) s_org[tid] = origin[tid];
  __syncthreads();

  int n = blockIdx.x * blockDim.x + tid;
  double rz = 0.0, rz2 = 0.0, rv = 0.0;
  if (n < N) {
    int4 cd = coords[n];
    int pos = atomicAdd(&ofs[voxel_key(cd)], 1);
    sorted[pos] = make_int4(cd.y, cd.z, cd.w, n);
    float wx = (float)cd.y * VOXSZ + s_org[0];
    float wy = (float)cd.z * VOXSZ + s_org[1];
    float wz = (float)cd.w * VOXSZ + s_org[2];
    float zs = 0.f; int cnt = 0;
#pragma unroll
    for (int v = 0; v < NV; ++v) {
      const float* P = &s_proj[v * 12];
      float ix = P[0] * wx + P[1] * wy + P[2]  * wz + P[3];
      float iy = P[4] * wx + P[5] * wy + P[6]  * wz + P[7];
      float iz = P[8] * wx + P[9] * wy + P[10] * wz + P[11];
      float px = ix / iz, py = iy / iz;
      bool inb = (px >= 0.f) && (px <= (float)(NW - 1)) &&
                 (py >= 0.f) && (py <= (float)(NH - 1)) && (iz > 0.f);
      if (inb) { cnt++; zs += iz; }
    }
    if (cnt > 0) {
      float zsv = zs / (float)cnt;
      rz = (double)zsv; rz2 = (double)zsv * (double)zsv; rv = 1.0;
    }
  }
#pragma unroll
  for (int off = 32; off > 0; off >>= 1) {
    rz  += __shfl_down(rz,  off, 64);
    rz2 += __shfl_down(rz2, off, 64);
    rv  += __shfl_down(rv,  off, 64);
  }
  if ((tid & 63) == 0) {
    int w = tid >> 6;
    s_red[0][w] = rz; s_red[1][w] = rz2; s_red[2][w] = rv;
  }
  __syncthreads();
  if (tid == 0) {
    double a = 0, b = 0, c = 0;
#pragma unroll
    for (int w = 0; w < 4; ++w) { a += s_red[0][w]; b += s_red[1][w]; c += s_red[2][w]; }
    double* p = partials + (size_t)blockIdx.x * 4;
    p[0] = a; p[1] = b; p[2] = c;
  }
}

// projection-only stats (fallback path)
__global__ __launch_bounds__(256)
void stats_k(const int4* __restrict__ coords, const float* __restrict__ origin,
             const float* __restrict__ proj, double* __restrict__ partials, int N) {
  __shared__ float s_proj[NV * 12];
  __shared__ float s_org[3];
  __shared__ double s_red[3][4];
  int tid = threadIdx.x;
  if (tid < NV * 12) s_proj[tid] = proj[(tid / 12) * 16 + (tid % 12)];
  if (tid < 3) s_org[tid] = origin[tid];
  __syncthreads();
  int n = blockIdx.x * blockDim.x + tid;
  double rz = 0.0, rz2 = 0.0, rv = 0.0;
  if (n < N) {
    int4 cd = coords[n];
    float wx = (float)cd.y * VOXSZ + s_org[0];
    float wy = (float)cd.z * VOXSZ + s_org[1];
    float wz = (float)cd.w * VOXSZ + s_org[2];
    float zs = 0.f; int cnt = 0;
#pragma unroll
    for (int v = 0; v < NV; ++v) {
      const float* P = &s_proj[v * 12];
      float ix = P[0] * wx + P[1] * wy + P[2]  * wz + P[3];
      float iy = P[4] * wx + P[5] * wy + P[6]  * wz + P[7];
      float iz = P[8] * wx + P[9] * wy + P[10] * wz + P[11];
      float px = ix / iz, py = iy / iz;
      bool inb = (px >= 0.f) && (px <= (float)(NW - 1)) &&
                 (py >= 0.f) && (py <= (float)(NH - 1)) && (iz > 0.f);
      if (inb) { cnt++; zs += iz; }
    }
    if (cnt > 0) {
      float zsv = zs / (float)cnt;
      rz = (double)zsv; rz2 = (double)zsv * (double)zsv; rv = 1.0;
    }
  }
#pragma unroll
  for (int off = 32; off > 0; off >>= 1) {
    rz  += __shfl_down(rz,  off, 64);
    rz2 += __shfl_down(rz2, off, 64);
    rv  += __shfl_down(rv,  off, 64);
  }
  if ((tid & 63) == 0) {
    int w = tid >> 6;
    s_red[0][w] = rz; s_red[1][w] = rz2; s_red[2][w] = rv;
  }
  __syncthreads();
  if (tid == 0) {
    double a = 0, b = 0, c = 0;
#pragma unroll
    for (int w = 0; w < 4; ++w) { a += s_red[0][w]; b += s_red[1][w]; c += s_red[2][w]; }
    double* p = partials + (size_t)blockIdx.x * 4;
    p[0] = a; p[1] = b; p[2] = c;
  }
}

// single block: sum partials, compute zmean/zstd
__global__ __launch_bounds__(1024)
void reduce_finalize_k(const double* __restrict__ partials, int nblocks,
                       float* __restrict__ scal) {
  int tid = threadIdx.x;
  double rz = 0.0, rz2 = 0.0, rv = 0.0;
  for (int i = tid; i < nblocks; i += 1024) {
    const double* p = partials + (size_t)i * 4;
    rz += p[0]; rz2 += p[1]; rv += p[2];
  }
#pragma unroll
  for (int off = 32; off > 0; off >>= 1) {
    rz  += __shfl_down(rz,  off, 64);
    rz2 += __shfl_down(rz2, off, 64);
    rv  += __shfl_down(rv,  off, 64);
  }
  __shared__ double s[3][16];
  if ((tid & 63) == 0) {
    int w = tid >> 6;
    s[0][w] = rz; s[1][w] = rz2; s[2][w] = rv;
  }
  __syncthreads();
  if (tid == 0) {
    double sz = 0, sz2 = 0, nv = 0;
#pragma unroll
    for (int w = 0; w < 16; ++w) { sz += s[0][w]; sz2 += s[1][w]; nv += s[2][w]; }
    double nvm = (nv > 1.0) ? nv : 1.0;
    double zmean = sz / nvm;
    double var = sz2 - 2.0 * zmean * sz + zmean * zmean * nv;
    if (var < 0.0) var = 0.0;
    double zstd = sqrt(var) + 1e-5;
    scal[0] = (float)zmean;
    scal[1] = (float)zstd;
  }
}

// f32 (V,C,H,W) -> fp16 (V,H,W, dense 48 B channel block), LDS-tiled
__global__ __launch_bounds__(256)
void transpose_feats_k(const float* __restrict__ in, __half* __restrict__ outT) {
  int vh = blockIdx.x;            // v*NH + h
  int v = vh / NH, h = vh % NH;
  __shared__ __half s[NC][NW + 2];
  const float* ibase = in + (size_t)v * NC * NH * NW + (size_t)h * NW;
  for (int e = threadIdx.x; e < NC * NW; e += 256) {
    int c = e / NW, w = e - c * NW;
    s[c][w] = __float2half(ibase[(size_t)c * NH * NW + w]);
  }
  __syncthreads();
  unsigned int* obase = (unsigned int*)outT + (size_t)vh * NW * 12;
  for (int j = threadIdx.x; j < NW * 12; j += 256) {
    int w = j / 12, k = j - (j / 12) * 12;
    __half2 hv = __halves2half2(s[2 * k][w], s[2 * k + 1][w]);
    obase[j] = *(unsigned int*)&hv;
  }
}

__device__ __forceinline__ void unpack8(float4 a, float w, float* acc) {
  const __half2* h = (const __half2*)&a;
#pragma unroll
  for (int i = 0; i < 4; ++i) {
    float2 t = __half22float2(h[i]);
    acc[2 * i] += w * t.x; acc[2 * i + 1] += w * t.y;
  }
}

// Main gather: 3 threads per voxel (8 channels each), blockDim=192 (3 waves:
// wave p handles channels [8p,8p+8) for 64 consecutive sorted voxels).
__global__ __launch_bounds__(192, 8)
void bp_gather_k(const int4* __restrict__ sorted, const float* __restrict__ origin,
                 const float* __restrict__ proj, const __half* __restrict__ featsT,
                 const float* __restrict__ scal, float* __restrict__ out, int N) {
  __shared__ float s_proj[NV * 12];
  __shared__ float s_org[3];
  __shared__ float s_scal[2];
  int tid = threadIdx.x;
  if (tid < NV * 12) s_proj[tid] = proj[(tid / 12) * 16 + (tid % 12)];
  if (tid < 3) s_org[tid] = origin[tid];
  if (tid < 2) s_scal[tid] = scal[tid];
  __syncthreads();

  int nwg = gridDim.x, orig = blockIdx.x;
  int xcd = orig & 7, q = nwg >> 3, r = nwg & 7;
  int bid = (xcd < r ? xcd * (q + 1) : r * (q + 1) + (xcd - r) * q) + (orig >> 3);

  int lane = tid & 63, part = tid >> 6;
  int i = bid * 64 + lane;
  if (i >= N) return;
  int4 rec = sorted[i];
  int n = rec.w;

  float wx = (float)rec.x * VOXSZ + s_org[0];
  float wy = (float)rec.y * VOXSZ + s_org[1];
  float wz = (float)rec.z * VOXSZ + s_org[2];

  float acc[8];
#pragma unroll
  for (int c = 0; c < 8; ++c) acc[c] = 0.f;
  float zs = 0.f; int cnt = 0;
  const char* fbase = (const char*)featsT + part * 16;

#pragma unroll
  for (int v = 0; v < NV; ++v) {
    const float* P = &s_proj[v * 12];
    float ix = P[0] * wx + P[1] * wy + P[2]  * wz + P[3];
    float iy = P[4] * wx + P[5] * wy + P[6]  * wz + P[7];
    float iz = P[8] * wx + P[9] * wy + P[10] * wz + P[11];
    float px = ix / iz, py = iy / iz;
    bool inb = (px >= 0.f) && (px <= (float)(NW - 1)) &&
               (py >= 0.f) && (py <= (float)(NH - 1)) && (iz > 0.f);
    if (!inb) continue;
    cnt++; zs += iz;
    float x0f = floorf(px), y0f = floorf(py);
    float fx1 = px - x0f, fy1 = py - y0f;
    float fx0 = 1.f - fx1, fy0 = 1.f - fy1;
    int x0 = (int)x0f, y0 = (int)y0f;
    // x1==NW (y1==NH) only when weight is exactly 0 -> reuse x0 (dx=0) is exact
    int dx = (x0 + 1 < NW) ? 48 : 0;
    int dy = (y0 + 1 < NH) ? NW * 48 : 0;
    const char* p00 = fbase + (size_t)((y0 + v * NH) * NW + x0) * 48;
    float w00 = fx0 * fy0, w10 = fx1 * fy0, w01 = fx0 * fy1, w11 = fx1 * fy1;
    float4 c00 = *(const float4*)p00;
    float4 c10 = *(const float4*)(p00 + dx);
    float4 c01 = *(const float4*)(p00 + dy);
    float4 c11 = *(const float4*)(p00 + dx + dy);
    unpack8(c00, w00, acc);
    unpack8(c10, w10, acc);
    unpack8(c01, w01, acc);
    unpack8(c11, w11, acc);
  }

  float denom = (cnt > 0) ? (float)cnt : 1.f;
  float inv = 1.f / denom;
  size_t row = (size_t)n * (NC + 1) + part * 8;
#pragma unroll
  for (int c = 0; c < 8; ++c) out[row + c] = acc[c] * inv;
  if (part == 2) {
    float zsv = zs * inv;
    out[(size_t)n * (NC + 1) + NC] = (cnt > 0) ? (zsv - s_scal[0]) / s_scal[1] : 0.f;
  }
  if (part == 0) out[(size_t)N * (NC + 1) + n] = (float)cnt;
}

// Fallback (ws too small): 1 thread/voxel, f32 strided gather from original feats.
__global__ __launch_bounds__(256)
void bp_fallback_k(const int4* __restrict__ coords, const float* __restrict__ origin,
                   const float* __restrict__ proj, const float* __restrict__ feats,
                   const float* __restrict__ scal, float* __restrict__ out, int N) {
  __shared__ float s_proj[NV * 12];
  __shared__ float s_org[3];
  __shared__ float s_scal[2];
  int tid = threadIdx.x;
  if (tid < NV * 12) s_proj[tid] = proj[(tid / 12) * 16 + (tid % 12)];
  if (tid < 3) s_org[tid] = origin[tid];
  if (tid < 2) s_scal[tid] = scal[tid];
  __syncthreads();
  int n = blockIdx.x * blockDim.x + tid;
  if (n >= N) return;
  int4 cd = coords[n];
  float wx = (float)cd.y * VOXSZ + s_org[0];
  float wy = (float)cd.z * VOXSZ + s_org[1];
  float wz = (float)cd.w * VOXSZ + s_org[2];
  float acc[NC];
#pragma unroll
  for (int c = 0; c < NC; ++c) acc[c] = 0.f;
  float zs = 0.f; int cnt = 0;
#pragma unroll
  for (int v = 0; v < NV; ++v) {
    const float* P = &s_proj[v * 12];
    float ix = P[0] * wx + P[1] * wy + P[2]  * wz + P[3];
    float iy = P[4] * wx + P[5] * wy + P[6]  * wz + P[7];
    float iz = P[8] * wx + P[9] * wy + P[10] * wz + P[11];
    float px = ix / iz, py = iy / iz;
    bool inb = (px >= 0.f) && (px <= (float)(NW - 1)) &&
               (py >= 0.f) && (py <= (float)(NH - 1)) && (iz > 0.f);
    if (!inb) continue;
    cnt++; zs += iz;
    float x0f = floorf(px), y0f = floorf(py);
    float fx1 = px - x0f, fy1 = py - y0f;
    float fx0 = 1.f - fx1, fy0 = 1.f - fy1;
    int x0 = (int)x0f, y0 = (int)y0f;
    int x1 = (x0 + 1 < NW) ? x0 + 1 : NW - 1;
    int y1 = (y0 + 1 < NH) ? y0 + 1 : NH - 1;
    float w00 = fx0 * fy0, w10 = fx1 * fy0, w01 = fx0 * fy1, w11 = fx1 * fy1;
    const float* base = feats + (size_t)v * NC * NH * NW;
#pragma unroll
    for (int c = 0; c < NC; ++c) {
      const float* pc = base + (size_t)c * NH * NW;
      acc[c] += pc[y0 * NW + x0] * w00 + pc[y0 * NW + x1] * w10 +
                pc[y1 * NW + x0] * w01 + pc[y1 * NW + x1] * w11;
    }
  }
  float denom = (cnt > 0) ? (float)cnt : 1.f;
  float inv = 1.f / denom;
  size_t row = (size_t)n * (NC + 1);
#pragma unroll
  for (int c = 0; c < NC; ++c) out[row + c] = acc[c] * inv;
  float zsv = zs * inv;
  out[row + NC] = (cnt > 0) ? (zsv - s_scal[0]) / s_scal[1] : 0.f;
  out[(size_t)N * (NC + 1) + n] = (float)cnt;
}

extern "C" void kernel_launch(void* const* d_in, const int* in_sizes, int n_in,
                              void* d_out, int out_size, void* d_ws, size_t ws_size,
                              hipStream_t stream) {
  const int4*  coords = (const int4*)d_in[0];
  const float* origin = (const float*)d_in[1];
  const float* feats  = (const float*)d_in[2];
  const float* proj   = (const float*)d_in[3];
  float* out = (float*)d_out;
  int N = in_sizes[0] / 4;

  int blocksAll = (N + 255) / 256;

  char* ws = (char*)d_ws;
  float*  scal     = (float*)ws;                 // 2 floats
  double* partials = (double*)(ws + 64);
  size_t off = 64 + (size_t)blocksAll * 4 * sizeof(double);
  off = (off + 63) & ~(size_t)63;
  __half* featsT = (__half*)(ws + off);
  off += (size_t)NV * NH * NW * 48;              // dense 48 B per pixel
  int* hist = (int*)(ws + off); off += NBINS * sizeof(int);
  int* ofs  = (int*)(ws + off); off += NBINS * sizeof(int);
  off = (off + 15) & ~(size_t)15;
  int4* sorted = (int4*)(ws + off); off += (size_t)N * sizeof(int4);
  bool full = (ws_size >= off);

  if (full) {
    hipMemsetAsync(hist, 0, NBINS * sizeof(int), stream);
    hist_k<<<blocksAll, 256, 0, stream>>>(coords, hist, N);
    transpose_feats_k<<<NV * NH, 256, 0, stream>>>(feats, featsT);
    scan_k<<<1, 1024, 0, stream>>>(hist, ofs);
    scatter_stats_k<<<blocksAll, 256, 0, stream>>>(coords, origin, proj, ofs, sorted, partials, N);
    reduce_finalize_k<<<1, 1024, 0, stream>>>(partials, blocksAll, scal);
    int gblocks = (N + 63) / 64;
    bp_gather_k<<<gblocks, 192, 0, stream>>>(sorted, origin, proj, featsT, scal, out, N);
  } else {
    stats_k<<<blocksAll, 256, 0, stream>>>(coords, origin, proj, partials, N);
    reduce_finalize_k<<<1, 1024, 0, stream>>>(partials, blocksAll, scal);
    bp_fallback_k<<<blocksAll, 256, 0, stream>>>(coords, origin, proj, feats, scal, out, N);
  }
}

// Round 6
// 113.808 us; speedup vs baseline: 2.4480x; 1.0917x over previous
//
#include <hip/hip_runtime.h>
#include <hip/hip_fp16.h>
#include <math.h>

#define VOXSZ 0.04f
#define NV 9
#define NC 24
#define NH 120
#define NW 160
#define NBINS 32768      // 15-bit morton key of (x>>2, y>>2, z>>2), each 0..16
#define TBLOCKS (NV * NH)  // 1080 transpose blocks in prep_k

// ---------------------------------------------------------------------------
// ws layout:
//   [0,64):  2 f32 scalars (zmean, zstd)
//   [64,+):  per-block partials (4 doubles each)
//   then:    featsT fp16 48 B/pixel (ch0..23 dense), hist[NBINS], ofs[NBINS],
//            sorted[N] int2 records (packed xyz, orig index)
// ---------------------------------------------------------------------------

__device__ __forceinline__ int morton5(int a) {
  a = (a | (a << 8)) & 0x100F;
  a = (a | (a << 4)) & 0x10C3;
  a = (a | (a << 2)) & 0x1249;
  return a;
}

__device__ __forceinline__ int voxel_key(int4 cd) {
  int xc = cd.y >> 2, yc = cd.z >> 2, zc = cd.w >> 2;
  xc = min(max(xc, 0), 16); yc = min(max(yc, 0), 16); zc = min(max(zc, 0), 16);
  return morton5(xc) | (morton5(yc) << 1) | (morton5(zc) << 2);
}

// Fused prep: blocks [0,TBLOCKS) transpose feats; blocks [TBLOCKS,..) do
// histogram + per-block depth-stat partials (independent work, one dispatch).
__global__ __launch_bounds__(256)
void prep_k(const float* __restrict__ feats, __half* __restrict__ outT,
            const int4* __restrict__ coords, const float* __restrict__ origin,
            const float* __restrict__ proj, int* __restrict__ hist,
            double* __restrict__ partials, int N) {
  __shared__ __half s[NC][NW + 2];
  __shared__ float s_proj[NV * 12];
  __shared__ float s_org[3];
  __shared__ double s_red[3][4];
  int tid = threadIdx.x;

  if (blockIdx.x < TBLOCKS) {
    // --- transpose role: f32 (V,C,H,W) -> fp16 (V,H,W, dense 48B block) ---
    int vh = blockIdx.x;
    int v = vh / NH, h = vh % NH;
    const float* ibase = feats + (size_t)v * NC * NH * NW + (size_t)h * NW;
    for (int e = tid; e < NC * NW; e += 256) {
      int c = e / NW, w = e - c * NW;
      s[c][w] = __float2half(ibase[(size_t)c * NH * NW + w]);
    }
    __syncthreads();
    unsigned int* obase = (unsigned int*)outT + (size_t)vh * NW * 12;
    for (int j = tid; j < NW * 12; j += 256) {
      int w = j / 12, k = j - (j / 12) * 12;
      __half2 hv = __halves2half2(s[2 * k][w], s[2 * k + 1][w]);
      obase[j] = *(unsigned int*)&hv;
    }
    return;
  }

  // --- hist + stats role ---
  if (tid < NV * 12) s_proj[tid] = proj[(tid / 12) * 16 + (tid % 12)];
  if (tid < 3) s_org[tid] = origin[tid];
  __syncthreads();

  int sid = blockIdx.x - TBLOCKS;
  int n = sid * 256 + tid;
  double rz = 0.0, rz2 = 0.0, rv = 0.0;
  if (n < N) {
    int4 cd = coords[n];
    atomicAdd(&hist[voxel_key(cd)], 1);
    float wx = (float)cd.y * VOXSZ + s_org[0];
    float wy = (float)cd.z * VOXSZ + s_org[1];
    float wz = (float)cd.w * VOXSZ + s_org[2];
    float zs = 0.f; int cnt = 0;
#pragma unroll
    for (int v = 0; v < NV; ++v) {
      const float* P = &s_proj[v * 12];
      float ix = P[0] * wx + P[1] * wy + P[2]  * wz + P[3];
      float iy = P[4] * wx + P[5] * wy + P[6]  * wz + P[7];
      float iz = P[8] * wx + P[9] * wy + P[10] * wz + P[11];
      float px = ix / iz, py = iy / iz;
      bool inb = (px >= 0.f) && (px <= (float)(NW - 1)) &&
                 (py >= 0.f) && (py <= (float)(NH - 1)) && (iz > 0.f);
      if (inb) { cnt++; zs += iz; }
    }
    if (cnt > 0) {
      float zsv = zs / (float)cnt;
      rz = (double)zsv; rz2 = (double)zsv * (double)zsv; rv = 1.0;
    }
  }
#pragma unroll
  for (int off = 32; off > 0; off >>= 1) {
    rz  += __shfl_down(rz,  off, 64);
    rz2 += __shfl_down(rz2, off, 64);
    rv  += __shfl_down(rv,  off, 64);
  }
  if ((tid & 63) == 0) {
    int w = tid >> 6;
    s_red[0][w] = rz; s_red[1][w] = rz2; s_red[2][w] = rv;
  }
  __syncthreads();
  if (tid == 0) {
    double a = 0, b = 0, c = 0;
#pragma unroll
    for (int w = 0; w < 4; ++w) { a += s_red[0][w]; b += s_red[1][w]; c += s_red[2][w]; }
    double* p = partials + (size_t)sid * 4;
    p[0] = a; p[1] = b; p[2] = c;
  }
}

// block 0: exclusive scan hist->ofs; block 1: reduce partials -> zmean/zstd
__global__ __launch_bounds__(1024)
void scan_reduce_k(const int* __restrict__ hist, int* __restrict__ ofs,
                   const double* __restrict__ partials, int nblocks,
                   float* __restrict__ scal) {
  __shared__ int ssum[1024];
  __shared__ double s[3][16];
  int tid = threadIdx.x;

  if (blockIdx.x == 0) {
    int base = tid * 32;
    int acc = 0;
    for (int i = 0; i < 32; ++i) acc += hist[base + i];
    ssum[tid] = acc;
    __syncthreads();
    for (int off = 1; off < 1024; off <<= 1) {
      int v = (tid >= off) ? ssum[tid - off] : 0;
      __syncthreads();
      ssum[tid] += v;
      __syncthreads();
    }
    int pre = (tid == 0) ? 0 : ssum[tid - 1];
    for (int i = 0; i < 32; ++i) {
      int h = hist[base + i];
      ofs[base + i] = pre;
      pre += h;
    }
    return;
  }

  double rz = 0.0, rz2 = 0.0, rv = 0.0;
  for (int i = tid; i < nblocks; i += 1024) {
    const double* p = partials + (size_t)i * 4;
    rz += p[0]; rz2 += p[1]; rv += p[2];
  }
#pragma unroll
  for (int off = 32; off > 0; off >>= 1) {
    rz  += __shfl_down(rz,  off, 64);
    rz2 += __shfl_down(rz2, off, 64);
    rv  += __shfl_down(rv,  off, 64);
  }
  if ((tid & 63) == 0) {
    int w = tid >> 6;
    s[0][w] = rz; s[1][w] = rz2; s[2][w] = rv;
  }
  __syncthreads();
  if (tid == 0) {
    double sz = 0, sz2 = 0, nv = 0;
#pragma unroll
    for (int w = 0; w < 16; ++w) { sz += s[0][w]; sz2 += s[1][w]; nv += s[2][w]; }
    double nvm = (nv > 1.0) ? nv : 1.0;
    double zmean = sz / nvm;
    double var = sz2 - 2.0 * zmean * sz + zmean * zmean * nv;
    if (var < 0.0) var = 0.0;
    double zstd = sqrt(var) + 1e-5;
    scal[0] = (float)zmean;
    scal[1] = (float)zstd;
  }
}

// pure scatter: packed records (x | y<<7 | z<<14, n)
__global__ __launch_bounds__(256)
void scatter_k(const int4* __restrict__ coords, int* __restrict__ ofs,
               int2* __restrict__ sorted, int N) {
  int n = blockIdx.x * blockDim.x + threadIdx.x;
  if (n >= N) return;
  int4 cd = coords[n];
  int pos = atomicAdd(&ofs[voxel_key(cd)], 1);
  sorted[pos] = make_int2(cd.y | (cd.z << 7) | (cd.w << 14), n);
}

// Main gather: 3 threads per voxel (8 channels each), packed fp16 accumulate.
__global__ __launch_bounds__(192, 8)
void bp_gather_k(const int2* __restrict__ sorted, const float* __restrict__ origin,
                 const float* __restrict__ proj, const __half* __restrict__ featsT,
                 const float* __restrict__ scal, float* __restrict__ out, int N) {
  __shared__ float s_proj[NV * 12];
  __shared__ float s_org[3];
  __shared__ float s_scal[2];
  int tid = threadIdx.x;
  if (tid < NV * 12) s_proj[tid] = proj[(tid / 12) * 16 + (tid % 12)];
  if (tid < 3) s_org[tid] = origin[tid];
  if (tid < 2) s_scal[tid] = scal[tid];
  __syncthreads();

  int nwg = gridDim.x, orig = blockIdx.x;
  int xcd = orig & 7, q = nwg >> 3, r = nwg & 7;
  int bid = (xcd < r ? xcd * (q + 1) : r * (q + 1) + (xcd - r) * q) + (orig >> 3);

  int lane = tid & 63, part = tid >> 6;
  int i = bid * 64 + lane;
  if (i >= N) return;
  int2 rec = sorted[i];
  int xi = rec.x & 127, yi = (rec.x >> 7) & 127, zi = (rec.x >> 14) & 127;
  int n = rec.y;

  float wx = (float)xi * VOXSZ + s_org[0];
  float wy = (float)yi * VOXSZ + s_org[1];
  float wz = (float)zi * VOXSZ + s_org[2];

  __half2 acc2[4];
  const __half2 zero2 = __float2half2_rn(0.f);
#pragma unroll
  for (int c = 0; c < 4; ++c) acc2[c] = zero2;
  float zs = 0.f; int cnt = 0;
  const char* fbase = (const char*)featsT + part * 16;

#pragma unroll
  for (int v = 0; v < NV; ++v) {
    const float* P = &s_proj[v * 12];
    float ix = P[0] * wx + P[1] * wy + P[2]  * wz + P[3];
    float iy = P[4] * wx + P[5] * wy + P[6]  * wz + P[7];
    float iz = P[8] * wx + P[9] * wy + P[10] * wz + P[11];
    float px = ix / iz, py = iy / iz;
    bool inb = (px >= 0.f) && (px <= (float)(NW - 1)) &&
               (py >= 0.f) && (py <= (float)(NH - 1)) && (iz > 0.f);
    if (!inb) continue;
    cnt++; zs += iz;
    float x0f = floorf(px), y0f = floorf(py);
    float fx1 = px - x0f, fy1 = py - y0f;
    float fx0 = 1.f - fx1, fy0 = 1.f - fy1;
    int x0 = (int)x0f, y0 = (int)y0f;
    // x1==NW (y1==NH) only when weight is exactly 0 -> reuse x0 (dx=0) is exact
    int dx = (x0 + 1 < NW) ? 48 : 0;
    int dy = (y0 + 1 < NH) ? NW * 48 : 0;
    const char* p00 = fbase + (size_t)((y0 + v * NH) * NW + x0) * 48;
    float w00 = fx0 * fy0, w10 = fx1 * fy0, w01 = fx0 * fy1, w11 = fx1 * fy1;
    float4 c00 = *(const float4*)p00;
    float4 c10 = *(const float4*)(p00 + dx);
    float4 c01 = *(const float4*)(p00 + dy);
    float4 c11 = *(const float4*)(p00 + dx + dy);
    __half2 w2;
    const __half2* h00 = (const __half2*)&c00;
    const __half2* h10 = (const __half2*)&c10;
    const __half2* h01 = (const __half2*)&c01;
    const __half2* h11 = (const __half2*)&c11;
    w2 = __float2half2_rn(w00);
#pragma unroll
    for (int c = 0; c < 4; ++c) acc2[c] = __hfma2(w2, h00[c], acc2[c]);
    w2 = __float2half2_rn(w10);
#pragma unroll
    for (int c = 0; c < 4; ++c) acc2[c] = __hfma2(w2, h10[c], acc2[c]);
    w2 = __float2half2_rn(w01);
#pragma unroll
    for (int c = 0; c < 4; ++c) acc2[c] = __hfma2(w2, h01[c], acc2[c]);
    w2 = __float2half2_rn(w11);
#pragma unroll
    for (int c = 0; c < 4; ++c) acc2[c] = __hfma2(w2, h11[c], acc2[c]);
  }

  float denom = (cnt > 0) ? (float)cnt : 1.f;
  float inv = 1.f / denom;
  size_t row = (size_t)n * (NC + 1) + part * 8;
#pragma unroll
  for (int c = 0; c < 4; ++c) {
    float2 t = __half22float2(acc2[c]);
    out[row + 2 * c]     = t.x * inv;
    out[row + 2 * c + 1] = t.y * inv;
  }
  if (part == 2) {
    float zsv = zs * inv;
    out[(size_t)n * (NC + 1) + NC] = (cnt > 0) ? (zsv - s_scal[0]) / s_scal[1] : 0.f;
  }
  if (part == 0) out[(size_t)N * (NC + 1) + n] = (float)cnt;
}

// ---- fallback path (ws too small): projection stats + direct f32 gather ----
__global__ __launch_bounds__(256)
void stats_k(const int4* __restrict__ coords, const float* __restrict__ origin,
             const float* __restrict__ proj, double* __restrict__ partials, int N) {
  __shared__ float s_proj[NV * 12];
  __shared__ float s_org[3];
  __shared__ double s_red[3][4];
  int tid = threadIdx.x;
  if (tid < NV * 12) s_proj[tid] = proj[(tid / 12) * 16 + (tid % 12)];
  if (tid < 3) s_org[tid] = origin[tid];
  __syncthreads();
  int n = blockIdx.x * blockDim.x + tid;
  double rz = 0.0, rz2 = 0.0, rv = 0.0;
  if (n < N) {
    int4 cd = coords[n];
    float wx = (float)cd.y * VOXSZ + s_org[0];
    float wy = (float)cd.z * VOXSZ + s_org[1];
    float wz = (float)cd.w * VOXSZ + s_org[2];
    float zs = 0.f; int cnt = 0;
#pragma unroll
    for (int v = 0; v < NV; ++v) {
      const float* P = &s_proj[v * 12];
      float ix = P[0] * wx + P[1] * wy + P[2]  * wz + P[3];
      float iy = P[4] * wx + P[5] * wy + P[6]  * wz + P[7];
      float iz = P[8] * wx + P[9] * wy + P[10] * wz + P[11];
      float px = ix / iz, py = iy / iz;
      bool inb = (px >= 0.f) && (px <= (float)(NW - 1)) &&
                 (py >= 0.f) && (py <= (float)(NH - 1)) && (iz > 0.f);
      if (inb) { cnt++; zs += iz; }
    }
    if (cnt > 0) {
      float zsv = zs / (float)cnt;
      rz = (double)zsv; rz2 = (double)zsv * (double)zsv; rv = 1.0;
    }
  }
#pragma unroll
  for (int off = 32; off > 0; off >>= 1) {
    rz  += __shfl_down(rz,  off, 64);
    rz2 += __shfl_down(rz2, off, 64);
    rv  += __shfl_down(rv,  off, 64);
  }
  if ((tid & 63) == 0) {
    int w = tid >> 6;
    s_red[0][w] = rz; s_red[1][w] = rz2; s_red[2][w] = rv;
  }
  __syncthreads();
  if (tid == 0) {
    double a = 0, b = 0, c = 0;
#pragma unroll
    for (int w = 0; w < 4; ++w) { a += s_red[0][w]; b += s_red[1][w]; c += s_red[2][w]; }
    double* p = partials + (size_t)blockIdx.x * 4;
    p[0] = a; p[1] = b; p[2] = c;
  }
}

__global__ __launch_bounds__(1024)
void reduce_finalize_k(const double* __restrict__ partials, int nblocks,
                       float* __restrict__ scal) {
  int tid = threadIdx.x;
  double rz = 0.0, rz2 = 0.0, rv = 0.0;
  for (int i = tid; i < nblocks; i += 1024) {
    const double* p = partials + (size_t)i * 4;
    rz += p[0]; rz2 += p[1]; rv += p[2];
  }
#pragma unroll
  for (int off = 32; off > 0; off >>= 1) {
    rz  += __shfl_down(rz,  off, 64);
    rz2 += __shfl_down(rz2, off, 64);
    rv  += __shfl_down(rv,  off, 64);
  }
  __shared__ double s[3][16];
  if ((tid & 63) == 0) {
    int w = tid >> 6;
    s[0][w] = rz; s[1][w] = rz2; s[2][w] = rv;
  }
  __syncthreads();
  if (tid == 0) {
    double sz = 0, sz2 = 0, nv = 0;
#pragma unroll
    for (int w = 0; w < 16; ++w) { sz += s[0][w]; sz2 += s[1][w]; nv += s[2][w]; }
    double nvm = (nv > 1.0) ? nv : 1.0;
    double zmean = sz / nvm;
    double var = sz2 - 2.0 * zmean * sz + zmean * zmean * nv;
    if (var < 0.0) var = 0.0;
    double zstd = sqrt(var) + 1e-5;
    scal[0] = (float)zmean;
    scal[1] = (float)zstd;
  }
}

__global__ __launch_bounds__(256)
void bp_fallback_k(const int4* __restrict__ coords, const float* __restrict__ origin,
                   const float* __restrict__ proj, const float* __restrict__ feats,
                   const float* __restrict__ scal, float* __restrict__ out, int N) {
  __shared__ float s_proj[NV * 12];
  __shared__ float s_org[3];
  __shared__ float s_scal[2];
  int tid = threadIdx.x;
  if (tid < NV * 12) s_proj[tid] = proj[(tid / 12) * 16 + (tid % 12)];
  if (tid < 3) s_org[tid] = origin[tid];
  if (tid < 2) s_scal[tid] = scal[tid];
  __syncthreads();
  int n = blockIdx.x * blockDim.x + tid;
  if (n >= N) return;
  int4 cd = coords[n];
  float wx = (float)cd.y * VOXSZ + s_org[0];
  float wy = (float)cd.z * VOXSZ + s_org[1];
  float wz = (float)cd.w * VOXSZ + s_org[2];
  float acc[NC];
#pragma unroll
  for (int c = 0; c < NC; ++c) acc[c] = 0.f;
  float zs = 0.f; int cnt = 0;
#pragma unroll
  for (int v = 0; v < NV; ++v) {
    const float* P = &s_proj[v * 12];
    float ix = P[0] * wx + P[1] * wy + P[2]  * wz + P[3];
    float iy = P[4] * wx + P[5] * wy + P[6]  * wz + P[7];
    float iz = P[8] * wx + P[9] * wy + P[10] * wz + P[11];
    float px = ix / iz, py = iy / iz;
    bool inb = (px >= 0.f) && (px <= (float)(NW - 1)) &&
               (py >= 0.f) && (py <= (float)(NH - 1)) && (iz > 0.f);
    if (!inb) continue;
    cnt++; zs += iz;
    float x0f = floorf(px), y0f = floorf(py);
    float fx1 = px - x0f, fy1 = py - y0f;
    float fx0 = 1.f - fx1, fy0 = 1.f - fy1;
    int x0 = (int)x0f, y0 = (int)y0f;
    int x1 = (x0 + 1 < NW) ? x0 + 1 : NW - 1;
    int y1 = (y0 + 1 < NH) ? y0 + 1 : NH - 1;
    float w00 = fx0 * fy0, w10 = fx1 * fy0, w01 = fx0 * fy1, w11 = fx1 * fy1;
    const float* base = feats + (size_t)v * NC * NH * NW;
#pragma unroll
    for (int c = 0; c < NC; ++c) {
      const float* pc = base + (size_t)c * NH * NW;
      acc[c] += pc[y0 * NW + x0] * w00 + pc[y0 * NW + x1] * w10 +
                pc[y1 * NW + x0] * w01 + pc[y1 * NW + x1] * w11;
    }
  }
  float denom = (cnt > 0) ? (float)cnt : 1.f;
  float inv = 1.f / denom;
  size_t row = (size_t)n * (NC + 1);
#pragma unroll
  for (int c = 0; c < NC; ++c) out[row + c] = acc[c] * inv;
  float zsv = zs * inv;
  out[row + NC] = (cnt > 0) ? (zsv - s_scal[0]) / s_scal[1] : 0.f;
  out[(size_t)N * (NC + 1) + n] = (float)cnt;
}

extern "C" void kernel_launch(void* const* d_in, const int* in_sizes, int n_in,
                              void* d_out, int out_size, void* d_ws, size_t ws_size,
                              hipStream_t stream) {
  const int4*  coords = (const int4*)d_in[0];
  const float* origin = (const float*)d_in[1];
  const float* feats  = (const float*)d_in[2];
  const float* proj   = (const float*)d_in[3];
  float* out = (float*)d_out;
  int N = in_sizes[0] / 4;

  int blocksAll = (N + 255) / 256;

  char* ws = (char*)d_ws;
  float*  scal     = (float*)ws;                 // 2 floats
  double* partials = (double*)(ws + 64);
  size_t off = 64 + (size_t)blocksAll * 4 * sizeof(double);
  off = (off + 63) & ~(size_t)63;
  __half* featsT = (__half*)(ws + off);
  off += (size_t)NV * NH * NW * 48;              // dense 48 B per pixel
  int* hist = (int*)(ws + off); off += NBINS * sizeof(int);
  int* ofs  = (int*)(ws + off); off += NBINS * sizeof(int);
  off = (off + 15) & ~(size_t)15;
  int2* sorted = (int2*)(ws + off); off += (size_t)N * sizeof(int2);
  bool full = (ws_size >= off);

  if (full) {
    hipMemsetAsync(hist, 0, NBINS * sizeof(int), stream);
    prep_k<<<TBLOCKS + blocksAll, 256, 0, stream>>>(feats, featsT, coords, origin,
                                                    proj, hist, partials, N);
    scan_reduce_k<<<2, 1024, 0, stream>>>(hist, ofs, partials, blocksAll, scal);
    scatter_k<<<blocksAll, 256, 0, stream>>>(coords, ofs, sorted, N);
    int gblocks = (N + 63) / 64;
    bp_gather_k<<<gblocks, 192, 0, stream>>>(sorted, origin, proj, featsT, scal, out, N);
  } else {
    stats_k<<<blocksAll, 256, 0, stream>>>(coords, origin, proj, partials, N);
    reduce_finalize_k<<<1, 1024, 0, stream>>>(partials, blocksAll, scal);
    bp_fallback_k<<<blocksAll, 256, 0, stream>>>(coords, origin, proj, feats, scal, out, N);
  }
}